// Round 9
// baseline (163.633 us; speedup 1.0000x reference)
//
#include <hip/hip_runtime.h>
#include <hip/hip_bf16.h>
#include <math.h>

#define NPTS 4096
#define KNB 16
#define CAP 384
#define QPB 8   // R13/R17: p=2-paired QPB=8 attention structure is the fast one

typedef __attribute__((ext_vector_type(8))) short bf16x8;
typedef __attribute__((ext_vector_type(4))) float f32x4;
#define MFMA16(a, b, c) __builtin_amdgcn_mfma_f32_16x16x32_bf16(a, b, c, 0, 0, 0)

__device__ __forceinline__ unsigned short f2bf(float f) {
  unsigned int u = __float_as_uint(f);
  unsigned int r = (u + 0x7fffu + ((u >> 16) & 1u)) >> 16;
  return (unsigned short)r;
}
__device__ __forceinline__ float bf2f(unsigned short u) {
  return __uint_as_float((unsigned int)u << 16);
}

// ---------------------------------------------------------------------------
// Kernel 0 "pack": packs ALL weights to bf16 MFMA B-frag order + zero stats.
// ---------------------------------------------------------------------------
__global__ __launch_bounds__(256) void pack_kernel(
    const float* __restrict__ w_qkv, const float* __restrict__ w_a1,
    const float* __restrict__ w_a2, const float* __restrict__ w_p2,
    unsigned short* __restrict__ pkq, unsigned short* __restrict__ pk1,
    unsigned short* __restrict__ pk2, unsigned short* __restrict__ pkp,
    float* __restrict__ stats) {
  int e = blockIdx.x * 256 + threadIdx.x;
  if (e < 128) stats[e] = 0.f;
  if (e < 12288) {  // w_qkv [64][192]
    int j = e & 7, lane = (e >> 3) & 63, t = e >> 9;
    int ks = t & 1, nt = t >> 1;
    int k = ks * 32 + ((lane >> 4) << 3) + j, n = nt * 16 + (lane & 15);
    pkq[e] = f2bf(w_qkv[k * 192 + n]);
  } else if (e < 28672) {  // w_a1 [64][256]
    int e1 = e - 12288;
    int j = e1 & 7, lane = (e1 >> 3) & 63, t = e1 >> 9;
    int ks = t & 1, nt = t >> 1;
    int k = ks * 32 + ((lane >> 4) << 3) + j, n = nt * 16 + (lane & 15);
    pk1[e1] = f2bf(w_a1[k * 256 + n]);
  } else if (e < 45056) {  // w_a2 [256][64]
    int e2 = e - 28672;
    int j = e2 & 7, lane = (e2 >> 3) & 63, t = e2 >> 9;
    int ks = t & 7, nt = t >> 3;
    int k = ks * 32 + ((lane >> 4) << 3) + j, n = nt * 16 + (lane & 15);
    pk2[e2] = f2bf(w_a2[k * 64 + n]);
  } else if (e < 49152) {  // w_p2 [64][64]
    int e3 = e - 45056;
    int j = e3 & 7, lane = (e3 >> 3) & 63, t = e3 >> 9;
    int ks = t & 1, nt = t >> 1;
    int k = ks * 32 + ((lane >> 4) << 3) + j, n = nt * 16 + (lane & 15);
    pkp[e3] = f2bf(w_p2[k * 64 + n]);
  }
}

// ---------------------------------------------------------------------------
// Kernel 1 "qkv" (R20): qkv = x @ w_qkv + b_qkv via MFMA, now written as
// BF16 [8192][192] (3 MB, was f32 6 MB). The fused kernel's scattered K/V/q
// gathers then fit EVERY per-XCD 4MB L2 (qkv was 6MB -> heavy HBM misses at
// ~900cy; bf16 -> ~200cy L2 hits) and gather bytes halve.
// ---------------------------------------------------------------------------
__global__ __launch_bounds__(256) void qkv_kernel(
    const float* __restrict__ x, const unsigned short* __restrict__ pkq,
    const float* __restrict__ b_qkv, unsigned short* __restrict__ qkvh) {
  int tid = threadIdx.x, lane = tid & 63, w = tid >> 6;
  int m = lane & 15, quad = lane >> 4;
  int r0 = blockIdx.x * 16;

  const float* xr = x + (size_t)(r0 + m) * 64;
  float xa[8], xb[8];
  *(float4*)&xa[0] = *(const float4*)(xr + quad * 8);
  *(float4*)&xa[4] = *(const float4*)(xr + quad * 8 + 4);
  *(float4*)&xb[0] = *(const float4*)(xr + 32 + quad * 8);
  *(float4*)&xb[4] = *(const float4*)(xr + 32 + quad * 8 + 4);
  bf16x8 a0, a1;
#pragma unroll
  for (int j = 0; j < 8; ++j) {
    a0[j] = (short)f2bf(xa[j]);
    a1[j] = (short)f2bf(xb[j]);
  }

#pragma unroll
  for (int t = 0; t < 3; ++t) {
    int nt = w * 3 + t;
    bf16x8 b0 = *(const bf16x8*)(pkq + ((size_t)(nt * 2 + 0) * 64 + lane) * 8);
    bf16x8 b1 = *(const bf16x8*)(pkq + ((size_t)(nt * 2 + 1) * 64 + lane) * 8);
    int n = nt * 16 + m;
    f32x4 acc = {0.f, 0.f, 0.f, 0.f};
    acc = MFMA16(a0, b0, acc);
    acc = MFMA16(a1, b1, acc);
    float bb = b_qkv[n];
#pragma unroll
    for (int i = 0; i < 4; ++i)
      qkvh[(size_t)(r0 + quad * 4 + i) * 192 + n] = f2bf(acc[i] + bb);
  }
}

// ---------------------------------------------------------------------------
// Kernel 2 "fused" (v11 / R20): R16 monolith structure (the clean 60.6us
// baseline: loads at use sites -- R18/R19 proved the allocator re-sinks
// hoisted loads anyway) with all qkv gathers reading the BF16 buffer.
// __launch_bounds__(256,4): VGPR cap 128. R12: do NOT tighten (spill).
// ---------------------------------------------------------------------------
__global__ __launch_bounds__(256, 4) void fused_kernel(
    const unsigned short* __restrict__ qkvh, const float* __restrict__ pos,
    const unsigned short* __restrict__ pk1,
    const unsigned short* __restrict__ pk2,
    const unsigned short* __restrict__ pkp, const float* __restrict__ w_p1,
    const float* __restrict__ b_p1, const float* __restrict__ b_p2,
    const float* __restrict__ b_a1, const float* __restrict__ b_a2,
    const float* __restrict__ w_fc, const float* __restrict__ b_fc,
    float* __restrict__ y, float* __restrict__ stats) {
  __shared__ __align__(16) char smem[25216];
  __shared__ int s_idx[128];

  int tid = threadIdx.x, lane = tid & 63, w = tid >> 6;
  int m = lane & 15, quad = lane >> 4;
  int g0 = blockIdx.x * QPB;
  int b = g0 >> 12;
  const float* posb = pos + (size_t)b * NPTS * 3;

  // ======================= KNN phase =======================
  {
    unsigned int(*cbits)[CAP] = (unsigned int(*)[CAP])smem;            // 12288
    int(*cidx)[CAP] = (int(*)[CAP])(smem + 12288);                     // 12288
    unsigned long long* wmin = (unsigned long long*)(smem + 24576);    // 32
    float* sretry = (float*)(smem + 24608);                            // 32
    unsigned int* scnt = (unsigned int*)(smem + 24640);                // 32
    unsigned long long* sprev = (unsigned long long*)(smem + 24672);   // 8
    int* sany = (int*)(smem + 24680);                                  // 4
    float* st2 = (float*)(smem + 24688);                               // 32

    float qx[QPB], qy[QPB], qz[QPB], t2q[QPB];
#pragma unroll
    for (int q = 0; q < QPB; ++q) {
      int i = (g0 + q) & (NPTS - 1);
      qx[q] = posb[i * 3 + 0];
      qy[q] = posb[i * 3 + 1];
      qz[q] = posb[i * 3 + 2];
    }
    // adaptive radius, solved by threads 0..7 only; broadcast via LDS (R16).
    if (tid < QPB) {
      int i = (g0 + tid) & (NPTS - 1);
      float ax = posb[i * 3 + 0], ay = posb[i * 3 + 1], az = posb[i * 3 + 2];
      float r = 0.131f;
#pragma unroll
      for (int it = 0; it < 3; ++it) {
        float inv2r = 0.5f / r;
        float fx = (fminf(ax + r, 1.f) - fmaxf(ax - r, 0.f)) * inv2r;
        float fy = (fminf(ay + r, 1.f) - fmaxf(ay - r, 0.f)) * inv2r;
        float fz = (fminf(az + r, 1.f) - fmaxf(az - r, 0.f)) * inv2r;
        float expn = 17157.28f * r * r * r * fx * fy * fz;  // 4096*4pi/3
        float s = exp2f(0.33333334f * log2f(38.f / expn));
        s = fminf(fmaxf(s, 0.7f), 1.6f);
        r = fminf(r * s, 0.32f);
      }
      st2[tid] = r * r;
      scnt[tid] = 0;
    }
    if (tid == 0) sany[0] = 0;
    __syncthreads();
#pragma unroll
    for (int q = 0; q < QPB; ++q) t2q[q] = st2[q];

    for (int c = 0; c < NPTS / 256; ++c) {
      int j = c * 256 + tid;
      int j3 = j * 3;
      float px = posb[j3 + 0], py = posb[j3 + 1], pz = posb[j3 + 2];
#pragma unroll
      for (int q = 0; q < QPB; ++q) {
        float dx = qx[q] - px, dy = qy[q] - py, dz = qz[q] - pz;
        float d2 = fmaf(dz, dz, fmaf(dy, dy, dx * dx));
        bool hit = d2 < t2q[q];
        unsigned long long mask = __ballot(hit);
        if (mask) {  // wave-uniform skip
          if (hit) {
            unsigned int p = atomicAdd(&scnt[q], 1u);
            if (p < CAP) {
              cbits[q][p] = __float_as_uint(d2);
              cidx[q][p] = j;
            }
          }
        }
      }
    }
    __syncthreads();

    if (tid < QPB) {
      int q = tid;
      unsigned int n = scnt[q];
      float nt = 0.f;
      if (n < KNB) nt = st2[q] * 4.f;           // widen: 2x radius
      else if (n > CAP) nt = st2[q] * 0.4f;     // narrow
      sretry[q] = nt;
      if (nt != 0.f) {
        scnt[q] = 0;
        sany[0] = 1;
      }
    }
    __syncthreads();

    if (sany[0]) {  // statistically dead with adaptive radius; backstop
      float tr[QPB];
#pragma unroll
      for (int q = 0; q < QPB; ++q) tr[q] = sretry[q];
      for (int c = 0; c < NPTS / 256; ++c) {
        int j = c * 256 + tid;
        int j3 = j * 3;
        float px = posb[j3 + 0], py = posb[j3 + 1], pz = posb[j3 + 2];
#pragma unroll
        for (int q = 0; q < QPB; ++q) {
          if (tr[q] != 0.f) {
            float dx = qx[q] - px, dy = qy[q] - py, dz = qz[q] - pz;
            float d2 = fmaf(dz, dz, fmaf(dy, dy, dx * dx));
            bool hit = d2 < tr[q];
            unsigned long long mask = __ballot(hit);
            if (mask) {
              if (hit) {
                unsigned int p = atomicAdd(&scnt[q], 1u);
                if (p < CAP) {
                  cbits[q][p] = __float_as_uint(d2);
                  cidx[q][p] = j;
                }
              }
            }
          }
        }
      }
      __syncthreads();
    }

    // rank selection -> s_idx[q*16+rank]; wave w handles queries 2w, 2w+1
    for (int qq = 0; qq < 2; ++qq) {
      int q = w * 2 + qq;
      int L = (int)scnt[q];
      if (L >= KNB && L <= CAP) {
        for (int i = lane; i < L; i += 64) {
          unsigned long long ki = ((unsigned long long)cbits[q][i] << 32) |
                                  (unsigned int)cidx[q][i];
          int rank = 0;
          for (int mm = 0; mm < L; ++mm) {
            unsigned long long km = ((unsigned long long)cbits[q][mm] << 32) |
                                    (unsigned int)cidx[q][mm];
            rank += km < ki;
          }
          if (rank < KNB) s_idx[q * KNB + rank] = cidx[q][i];
        }
      }
    }
    __syncthreads();

    // exact fallback (block-uniform branch; pathological only)
    for (int q = 0; q < QPB; ++q) {
      unsigned int n = scnt[q];
      if (n < KNB || n > CAP) {
        unsigned long long prev = 0ull;
        for (int r = 0; r < KNB; ++r) {
          unsigned long long best = ~0ull;
          for (int c = 0; c < NPTS / 256; ++c) {
            int j = c * 256 + tid;
            float dx = qx[q] - posb[j * 3 + 0];
            float dy = qy[q] - posb[j * 3 + 1];
            float dz = qz[q] - posb[j * 3 + 2];
            float d2 = fmaf(dz, dz, fmaf(dy, dy, dx * dx));
            unsigned long long key =
                ((unsigned long long)__float_as_uint(d2) << 32) |
                (unsigned int)j;
            bool ok = (r == 0) || (key > prev);
            best = (ok && key < best) ? key : best;
          }
#pragma unroll
          for (int off = 32; off > 0; off >>= 1) {
            unsigned long long o = __shfl_down(best, off);
            best = best < o ? best : o;
          }
          if (lane == 0) wmin[w] = best;
          __syncthreads();
          if (tid == 0) {
            unsigned long long m0 = wmin[0], m1 = wmin[1];
            unsigned long long m2 = wmin[2], m3 = wmin[3];
            unsigned long long a = m0 < m1 ? m0 : m1;
            unsigned long long d = m2 < m3 ? m2 : m3;
            a = a < d ? a : d;
            s_idx[q * KNB + r] = (int)(unsigned int)a;
            sprev[0] = a;
          }
          __syncthreads();
          prev = sprev[0];
          __syncthreads();
        }
      }
    }
  }
  __syncthreads();  // knn scratch dead; s_idx valid

  // ======================= attention phase =======================
  unsigned short(*region)[72] = (unsigned short(*)[72])smem;        // 18432
  float(*s_rel)[32][3] = (float(*)[32][3])(smem + 18432);           // 1536

  // staging: rel (parallel 32-lane gather)
  if (lane < 32) {
    int row = 32 * w + lane;
    int p = lane >> 4;
    int g = g0 + 2 * w + p;
    int jb = (b << 12) | s_idx[row];
    s_rel[w][lane][0] = pos[(size_t)g * 3 + 0] - pos[(size_t)jb * 3 + 0];
    s_rel[w][lane][1] = pos[(size_t)g * 3 + 1] - pos[(size_t)jb * 3 + 1];
    s_rel[w][lane][2] = pos[(size_t)g * 3 + 2] - pos[(size_t)jb * 3 + 2];
  }

  // phase2: e = relu(rel @ w_p1 + b_p1) -> region (s_e), wave rows
  {
    float w0 = w_p1[lane], w1 = w_p1[64 + lane], w2 = w_p1[128 + lane];
    float bp = b_p1[lane];
    for (int rl = 0; rl < 32; ++rl) {
      int row = 32 * w + rl;
      float rx = s_rel[w][rl][0], ry = s_rel[w][rl][1], rz = s_rel[w][rl][2];
      float e = fmaf(rz, w2, fmaf(ry, w1, fmaf(rx, w0, bp)));
      region[row][lane] = f2bf(fmaxf(e, 0.f));
    }
  }

  // phase3: pe MFMA + h epilogue; s_h overwrites s_e (frags in regs first)
  {
    bf16x8 ea0[2], ea1[2];
#pragma unroll
    for (int p = 0; p < 2; ++p) {
      ea0[p] = *(const bf16x8*)&region[32 * w + 16 * p + m][quad * 8];
      ea1[p] = *(const bf16x8*)&region[32 * w + 16 * p + m][32 + quad * 8];
    }
#pragma unroll
    for (int nt = 0; nt < 4; ++nt) {
      bf16x8 b0 = *(const bf16x8*)(pkp + ((size_t)(nt * 2 + 0) * 64 + lane) * 8);
      bf16x8 b1 = *(const bf16x8*)(pkp + ((size_t)(nt * 2 + 1) * 64 + lane) * 8);
      int col = nt * 16 + m;
      float bp2 = b_p2[col];
#pragma unroll
      for (int p = 0; p < 2; ++p) {
        f32x4 acc = {0.f, 0.f, 0.f, 0.f};
        acc = MFMA16(ea0[p], b0, acc);
        acc = MFMA16(ea1[p], b1, acc);
        int g = g0 + 2 * w + p;
        float qv = bf2f(qkvh[(size_t)g * 192 + col]);
#pragma unroll
        for (int i = 0; i < 4; ++i) {
          int row = 32 * w + 16 * p + quad * 4 + i;
          int jb = (b << 12) | s_idx[row];
          float kv = bf2f(qkvh[(size_t)jb * 192 + 64 + col]);
          region[row][col] = f2bf(qv - kv + acc[i] + bp2);  // s_h
        }
      }
    }
  }

  // v prefetch into registers (latency hidden behind GEMM1/2 below)
  float vreg[2][4][4];
#pragma unroll
  for (int p = 0; p < 2; ++p)
#pragma unroll
    for (int i = 0; i < 4; ++i) {
      int row = 32 * w + 16 * p + quad * 4 + i;
      int jb = (b << 12) | s_idx[row];
      const unsigned short* vr = qkvh + (size_t)jb * 192 + 128;
#pragma unroll
      for (int nt2 = 0; nt2 < 4; ++nt2) vreg[p][nt2][i] = bf2f(vr[nt2 * 16 + m]);
    }

  // phase4+5: chunked GEMM1 -> s_tc (aliases own s_h rows) -> GEMM2 acc
  bf16x8 ha0[2], ha1[2];
#pragma unroll
  for (int p = 0; p < 2; ++p) {
    ha0[p] = *(const bf16x8*)&region[32 * w + 16 * p + m][quad * 8];
    ha1[p] = *(const bf16x8*)&region[32 * w + 16 * p + m][32 + quad * 8];
  }
  f32x4 acc2[2][4];
#pragma unroll
  for (int p = 0; p < 2; ++p)
#pragma unroll
    for (int nt2 = 0; nt2 < 4; ++nt2) acc2[p][nt2] = (f32x4){0.f, 0.f, 0.f, 0.f};

  unsigned short(*s_tc)[72] = (unsigned short(*)[72])(smem + w * 4608);

#pragma unroll
  for (int c = 0; c < 4; ++c) {
#pragma unroll
    for (int ntc = 0; ntc < 4; ++ntc) {
      int nt = 4 * c + ntc;
      bf16x8 b0 = *(const bf16x8*)(pk1 + ((size_t)(nt * 2 + 0) * 64 + lane) * 8);
      bf16x8 b1 = *(const bf16x8*)(pk1 + ((size_t)(nt * 2 + 1) * 64 + lane) * 8);
      int coll = ntc * 16 + m;
      float ba = b_a1[nt * 16 + m];
#pragma unroll
      for (int p = 0; p < 2; ++p) {
        f32x4 t = {0.f, 0.f, 0.f, 0.f};
        t = MFMA16(ha0[p], b0, t);
        t = MFMA16(ha1[p], b1, t);
#pragma unroll
        for (int i = 0; i < 4; ++i)
          s_tc[16 * p + quad * 4 + i][coll] = f2bf(fmaxf(t[i] + ba, 0.f));
      }
    }
#pragma unroll
    for (int sub = 0; sub < 2; ++sub) {
      int ks = c * 2 + sub;
      bf16x8 a[2];
#pragma unroll
      for (int p = 0; p < 2; ++p)
        a[p] = *(const bf16x8*)&s_tc[16 * p + m][sub * 32 + quad * 8];
#pragma unroll
      for (int nt2 = 0; nt2 < 4; ++nt2) {
        bf16x8 bb =
            *(const bf16x8*)(pk2 + ((size_t)(nt2 * 8 + ks) * 64 + lane) * 8);
#pragma unroll
        for (int p = 0; p < 2; ++p) acc2[p][nt2] = MFMA16(a[p], bb, acc2[p][nt2]);
      }
    }
  }

  // phase6: softmax over k (quad shuffles) + v-weighted sum (v from vreg)
  float ba2[4];
#pragma unroll
  for (int nt2 = 0; nt2 < 4; ++nt2) ba2[nt2] = b_a2[nt2 * 16 + m];
  float aggv[2][4];
#pragma unroll
  for (int p = 0; p < 2; ++p) {
#pragma unroll
    for (int nt2 = 0; nt2 < 4; ++nt2) {
      float sc[4];
#pragma unroll
      for (int i = 0; i < 4; ++i) sc[i] = acc2[p][nt2][i] + ba2[nt2];
      float mx = fmaxf(fmaxf(sc[0], sc[1]), fmaxf(sc[2], sc[3]));
      mx = fmaxf(mx, __shfl_xor(mx, 16));
      mx = fmaxf(mx, __shfl_xor(mx, 32));
      float ex[4], ss = 0.f;
#pragma unroll
      for (int i = 0; i < 4; ++i) {
        ex[i] = exp2f((sc[i] - mx) * 1.4426950408889634f);
        ss += ex[i];
      }
      ss += __shfl_xor(ss, 16);
      ss += __shfl_xor(ss, 32);
      float nu = 0.f;
#pragma unroll
      for (int i = 0; i < 4; ++i) nu = fmaf(ex[i], vreg[p][nt2][i], nu);
      nu += __shfl_xor(nu, 16);
      nu += __shfl_xor(nu, 32);
      aggv[p][nt2] = nu / ss;
    }
  }
  __syncthreads();  // all waves done with region -> reuse for agg/red

  float* s_agg = (float*)smem;  // [8][64]
  if (quad == 0) {
#pragma unroll
    for (int p = 0; p < 2; ++p)
#pragma unroll
      for (int nt2 = 0; nt2 < 4; ++nt2)
        s_agg[(2 * w + p) * 64 + nt2 * 16 + m] = aggv[p][nt2];
  }
  __syncthreads();

  // fc: thread (r=w, c=lane) handles rows w and w+4
  {
    int c = lane, r = w;
    float acc0 = b_fc[c], acc1 = b_fc[c];
    for (int d = 0; d < 64; ++d) {
      float wv = w_fc[d * 64 + c];
      acc0 = fmaf(s_agg[r * 64 + d], wv, acc0);
      acc1 = fmaf(s_agg[(r + 4) * 64 + d], wv, acc1);
    }
    y[(size_t)(g0 + r) * 64 + c] = acc0;
    y[(size_t)(g0 + r + 4) * 64 + c] = acc1;
    float* s_red = (float*)(smem + 2048);
    float* s_red2 = (float*)(smem + 3072);
    s_red[w * 64 + c] = acc0 + acc1;
    s_red2[w * 64 + c] = acc0 * acc0 + acc1 * acc1;
  }
  __syncthreads();
  if (tid < 64) {
    float* s_red = (float*)(smem + 2048);
    float* s_red2 = (float*)(smem + 3072);
    float s = s_red[tid] + s_red[64 + tid] + s_red[128 + tid] + s_red[192 + tid];
    float s2 =
        s_red2[tid] + s_red2[64 + tid] + s_red2[128 + tid] + s_red2[192 + tid];
    atomicAdd(&stats[tid], s);
    atomicAdd(&stats[64 + tid], s2);
  }
}

// ---------------------------------------------------------------------------
// Kernel 3: BN (batch stats) + relu + residual.
// ---------------------------------------------------------------------------
__global__ __launch_bounds__(256) void bn_kernel(
    const float* __restrict__ y, const float* __restrict__ x,
    const float* __restrict__ stats, const float* __restrict__ gamma,
    const float* __restrict__ beta, float* __restrict__ out) {
  size_t o = (size_t)blockIdx.x * 256 + threadIdx.x;
  int c = (int)(o & 63);
  const float inv_n = 1.f / 8192.f;
  float mean = stats[c] * inv_n;
  float var = stats[64 + c] * inv_n - mean * mean;
  float inv = rsqrtf(var + 1e-5f);
  float v = (y[o] - mean) * inv * gamma[c] + beta[c];
  out[o] = fmaxf(v, 0.f) + x[o];
}

// ---------------------------------------------------------------------------
extern "C" void kernel_launch(void* const* d_in, const int* in_sizes, int n_in,
                              void* d_out, int out_size, void* d_ws,
                              size_t ws_size, hipStream_t stream) {
  const float* x = (const float*)d_in[0];
  const float* pos = (const float*)d_in[1];
  const float* w_qkv = (const float*)d_in[2];
  const float* b_qkv = (const float*)d_in[3];
  const float* w_p1 = (const float*)d_in[4];
  const float* b_p1 = (const float*)d_in[5];
  const float* w_p2 = (const float*)d_in[6];
  const float* b_p2 = (const float*)d_in[7];
  const float* w_a1 = (const float*)d_in[8];
  const float* b_a1 = (const float*)d_in[9];
  const float* w_a2 = (const float*)d_in[10];
  const float* b_a2 = (const float*)d_in[11];
  const float* w_fc = (const float*)d_in[12];
  const float* b_fc = (const float*)d_in[13];
  const float* gamma = (const float*)d_in[14];
  const float* beta = (const float*)d_in[15];

  char* ws = (char*)d_ws;
  unsigned short* qkvh = (unsigned short*)(ws + 0);        // 3145728 B (bf16)
  float* y = (float*)(ws + 8912896);                       // 2097152 B
  float* stats = (float*)(ws + 11010048);                  // 512 B
  unsigned short* pk1 = (unsigned short*)(ws + 11010560);  // 32768 B
  unsigned short* pk2 = (unsigned short*)(ws + 11043328);  // 32768 B
  unsigned short* pkp = (unsigned short*)(ws + 11076096);  // 8192 B
  unsigned short* pkq = (unsigned short*)(ws + 11084288);  // 24576 B

  hipLaunchKernelGGL(pack_kernel, dim3(192), dim3(256), 0, stream, w_qkv,
                     w_a1, w_a2, w_p2, pkq, pk1, pk2, pkp, stats);
  hipLaunchKernelGGL(qkv_kernel, dim3(512), dim3(256), 0, stream, x, pkq,
                     b_qkv, qkvh);
  hipLaunchKernelGGL(fused_kernel, dim3(1024), dim3(256), 0, stream, qkvh,
                     pos, pk1, pk2, pkp, w_p1, b_p1, b_p2, b_a1, b_a2, w_fc,
                     b_fc, y, stats);
  hipLaunchKernelGGL(bn_kernel, dim3(2048), dim3(256), 0, stream, y, x, stats,
                     gamma, beta, (float*)d_out);
}

// Round 10
// 132.749 us; speedup vs baseline: 1.2326x; 1.2326x over previous
//
#include <hip/hip_runtime.h>
#include <hip/hip_bf16.h>
#include <math.h>

#define NPTS 4096
#define KNB 16
#define CAP 384
#define QPB 8   // R13/R17: p=2-paired QPB=8 attention structure is the fast one

typedef __attribute__((ext_vector_type(8))) short bf16x8;
typedef __attribute__((ext_vector_type(4))) float f32x4;
#define MFMA16(a, b, c) __builtin_amdgcn_mfma_f32_16x16x32_bf16(a, b, c, 0, 0, 0)

__device__ __forceinline__ unsigned short f2bf(float f) {
  unsigned int u = __float_as_uint(f);
  unsigned int r = (u + 0x7fffu + ((u >> 16) & 1u)) >> 16;
  return (unsigned short)r;
}

// ---------------------------------------------------------------------------
// Kernel 0 "pack": packs ALL weights to bf16 MFMA B-frag order + zero the
// 8-way-sharded stats (8*128 floats).
// ---------------------------------------------------------------------------
__global__ __launch_bounds__(256) void pack_kernel(
    const float* __restrict__ w_qkv, const float* __restrict__ w_a1,
    const float* __restrict__ w_a2, const float* __restrict__ w_p2,
    unsigned short* __restrict__ pkq, unsigned short* __restrict__ pk1,
    unsigned short* __restrict__ pk2, unsigned short* __restrict__ pkp,
    float* __restrict__ stats) {
  int e = blockIdx.x * 256 + threadIdx.x;
  if (e < 1024) stats[e] = 0.f;  // 8 shards x 128
  if (e < 12288) {  // w_qkv [64][192]
    int j = e & 7, lane = (e >> 3) & 63, t = e >> 9;
    int ks = t & 1, nt = t >> 1;
    int k = ks * 32 + ((lane >> 4) << 3) + j, n = nt * 16 + (lane & 15);
    pkq[e] = f2bf(w_qkv[k * 192 + n]);
  } else if (e < 28672) {  // w_a1 [64][256]
    int e1 = e - 12288;
    int j = e1 & 7, lane = (e1 >> 3) & 63, t = e1 >> 9;
    int ks = t & 1, nt = t >> 1;
    int k = ks * 32 + ((lane >> 4) << 3) + j, n = nt * 16 + (lane & 15);
    pk1[e1] = f2bf(w_a1[k * 256 + n]);
  } else if (e < 45056) {  // w_a2 [256][64]
    int e2 = e - 28672;
    int j = e2 & 7, lane = (e2 >> 3) & 63, t = e2 >> 9;
    int ks = t & 7, nt = t >> 3;
    int k = ks * 32 + ((lane >> 4) << 3) + j, n = nt * 16 + (lane & 15);
    pk2[e2] = f2bf(w_a2[k * 64 + n]);
  } else if (e < 49152) {  // w_p2 [64][64]
    int e3 = e - 45056;
    int j = e3 & 7, lane = (e3 >> 3) & 63, t = e3 >> 9;
    int ks = t & 1, nt = t >> 1;
    int k = ks * 32 + ((lane >> 4) << 3) + j, n = nt * 16 + (lane & 15);
    pkp[e3] = f2bf(w_p2[k * 64 + n]);
  }
}

// ---------------------------------------------------------------------------
// Kernel 1 "qkv": qkv = x @ w_qkv + b_qkv via MFMA (f32 output -- R20's bf16
// qkv REGRESSED fused 60->77us despite halving FETCH; reverted).
// ---------------------------------------------------------------------------
__global__ __launch_bounds__(256) void qkv_kernel(
    const float* __restrict__ x, const unsigned short* __restrict__ pkq,
    const float* __restrict__ b_qkv, float* __restrict__ qkv) {
  int tid = threadIdx.x, lane = tid & 63, w = tid >> 6;
  int m = lane & 15, quad = lane >> 4;
  int r0 = blockIdx.x * 16;

  const float* xr = x + (size_t)(r0 + m) * 64;
  float xa[8], xb[8];
  *(float4*)&xa[0] = *(const float4*)(xr + quad * 8);
  *(float4*)&xa[4] = *(const float4*)(xr + quad * 8 + 4);
  *(float4*)&xb[0] = *(const float4*)(xr + 32 + quad * 8);
  *(float4*)&xb[4] = *(const float4*)(xr + 32 + quad * 8 + 4);
  bf16x8 a0, a1;
#pragma unroll
  for (int j = 0; j < 8; ++j) {
    a0[j] = (short)f2bf(xa[j]);
    a1[j] = (short)f2bf(xb[j]);
  }

#pragma unroll
  for (int t = 0; t < 3; ++t) {
    int nt = w * 3 + t;
    bf16x8 b0 = *(const bf16x8*)(pkq + ((size_t)(nt * 2 + 0) * 64 + lane) * 8);
    bf16x8 b1 = *(const bf16x8*)(pkq + ((size_t)(nt * 2 + 1) * 64 + lane) * 8);
    int n = nt * 16 + m;
    f32x4 acc = {0.f, 0.f, 0.f, 0.f};
    acc = MFMA16(a0, b0, acc);
    acc = MFMA16(a1, b1, acc);
    float bb = b_qkv[n];
#pragma unroll
    for (int i = 0; i < 4; ++i)
      qkv[(size_t)(r0 + quad * 4 + i) * 192 + n] = acc[i] + bb;
  }
}

// ---------------------------------------------------------------------------
// Kernel 2 "fused" (v12 / R21): clean R16 structure (best measured: 60.3us)
// with ONE change: stats atomics sharded 8 ways. Old: 1024 blocks all
// atomicAdd the SAME 128 addresses -> ~50cy/add same-address serialization
// = ~21us bursty tail (fits: avg occupancy 30% despite all blocks resident,
// low VALU/MFMA/HBM). New: block adds to shard (bid&7) -> 128 adds/address.
// R18-R20 falsified the gather-latency family (prefetch neutral x2, bf16
// qkv regressed) -- do not revisit.
// __launch_bounds__(256,4): VGPR cap 128. R12: do NOT tighten (spill).
// ---------------------------------------------------------------------------
__global__ __launch_bounds__(256, 4) void fused_kernel(
    const float* __restrict__ qkv, const float* __restrict__ pos,
    const unsigned short* __restrict__ pk1,
    const unsigned short* __restrict__ pk2,
    const unsigned short* __restrict__ pkp, const float* __restrict__ w_p1,
    const float* __restrict__ b_p1, const float* __restrict__ b_p2,
    const float* __restrict__ b_a1, const float* __restrict__ b_a2,
    const float* __restrict__ w_fc, const float* __restrict__ b_fc,
    float* __restrict__ y, float* __restrict__ stats) {
  __shared__ __align__(16) char smem[25216];
  __shared__ int s_idx[128];

  int tid = threadIdx.x, lane = tid & 63, w = tid >> 6;
  int m = lane & 15, quad = lane >> 4;
  int g0 = blockIdx.x * QPB;
  int b = g0 >> 12;
  const float* posb = pos + (size_t)b * NPTS * 3;

  // ======================= KNN phase =======================
  {
    unsigned int(*cbits)[CAP] = (unsigned int(*)[CAP])smem;            // 12288
    int(*cidx)[CAP] = (int(*)[CAP])(smem + 12288);                     // 12288
    unsigned long long* wmin = (unsigned long long*)(smem + 24576);    // 32
    float* sretry = (float*)(smem + 24608);                            // 32
    unsigned int* scnt = (unsigned int*)(smem + 24640);                // 32
    unsigned long long* sprev = (unsigned long long*)(smem + 24672);   // 8
    int* sany = (int*)(smem + 24680);                                  // 4
    float* st2 = (float*)(smem + 24688);                               // 32

    float qx[QPB], qy[QPB], qz[QPB], t2q[QPB];
#pragma unroll
    for (int q = 0; q < QPB; ++q) {
      int i = (g0 + q) & (NPTS - 1);
      qx[q] = posb[i * 3 + 0];
      qy[q] = posb[i * 3 + 1];
      qz[q] = posb[i * 3 + 2];
    }
    // adaptive radius, solved by threads 0..7 only; broadcast via LDS (R16).
    if (tid < QPB) {
      int i = (g0 + tid) & (NPTS - 1);
      float ax = posb[i * 3 + 0], ay = posb[i * 3 + 1], az = posb[i * 3 + 2];
      float r = 0.131f;
#pragma unroll
      for (int it = 0; it < 3; ++it) {
        float inv2r = 0.5f / r;
        float fx = (fminf(ax + r, 1.f) - fmaxf(ax - r, 0.f)) * inv2r;
        float fy = (fminf(ay + r, 1.f) - fmaxf(ay - r, 0.f)) * inv2r;
        float fz = (fminf(az + r, 1.f) - fmaxf(az - r, 0.f)) * inv2r;
        float expn = 17157.28f * r * r * r * fx * fy * fz;  // 4096*4pi/3
        float s = exp2f(0.33333334f * log2f(38.f / expn));
        s = fminf(fmaxf(s, 0.7f), 1.6f);
        r = fminf(r * s, 0.32f);
      }
      st2[tid] = r * r;
      scnt[tid] = 0;
    }
    if (tid == 0) sany[0] = 0;
    __syncthreads();
#pragma unroll
    for (int q = 0; q < QPB; ++q) t2q[q] = st2[q];

    for (int c = 0; c < NPTS / 256; ++c) {
      int j = c * 256 + tid;
      int j3 = j * 3;
      float px = posb[j3 + 0], py = posb[j3 + 1], pz = posb[j3 + 2];
#pragma unroll
      for (int q = 0; q < QPB; ++q) {
        float dx = qx[q] - px, dy = qy[q] - py, dz = qz[q] - pz;
        float d2 = fmaf(dz, dz, fmaf(dy, dy, dx * dx));
        bool hit = d2 < t2q[q];
        unsigned long long mask = __ballot(hit);
        if (mask) {  // wave-uniform skip
          if (hit) {
            unsigned int p = atomicAdd(&scnt[q], 1u);
            if (p < CAP) {
              cbits[q][p] = __float_as_uint(d2);
              cidx[q][p] = j;
            }
          }
        }
      }
    }
    __syncthreads();

    if (tid < QPB) {
      int q = tid;
      unsigned int n = scnt[q];
      float nt = 0.f;
      if (n < KNB) nt = st2[q] * 4.f;           // widen: 2x radius
      else if (n > CAP) nt = st2[q] * 0.4f;     // narrow
      sretry[q] = nt;
      if (nt != 0.f) {
        scnt[q] = 0;
        sany[0] = 1;
      }
    }
    __syncthreads();

    if (sany[0]) {  // statistically dead with adaptive radius; backstop
      float tr[QPB];
#pragma unroll
      for (int q = 0; q < QPB; ++q) tr[q] = sretry[q];
      for (int c = 0; c < NPTS / 256; ++c) {
        int j = c * 256 + tid;
        int j3 = j * 3;
        float px = posb[j3 + 0], py = posb[j3 + 1], pz = posb[j3 + 2];
#pragma unroll
        for (int q = 0; q < QPB; ++q) {
          if (tr[q] != 0.f) {
            float dx = qx[q] - px, dy = qy[q] - py, dz = qz[q] - pz;
            float d2 = fmaf(dz, dz, fmaf(dy, dy, dx * dx));
            bool hit = d2 < tr[q];
            unsigned long long mask = __ballot(hit);
            if (mask) {
              if (hit) {
                unsigned int p = atomicAdd(&scnt[q], 1u);
                if (p < CAP) {
                  cbits[q][p] = __float_as_uint(d2);
                  cidx[q][p] = j;
                }
              }
            }
          }
        }
      }
      __syncthreads();
    }

    // rank selection -> s_idx[q*16+rank]; wave w handles queries 2w, 2w+1
    for (int qq = 0; qq < 2; ++qq) {
      int q = w * 2 + qq;
      int L = (int)scnt[q];
      if (L >= KNB && L <= CAP) {
        for (int i = lane; i < L; i += 64) {
          unsigned long long ki = ((unsigned long long)cbits[q][i] << 32) |
                                  (unsigned int)cidx[q][i];
          int rank = 0;
          for (int mm = 0; mm < L; ++mm) {
            unsigned long long km = ((unsigned long long)cbits[q][mm] << 32) |
                                    (unsigned int)cidx[q][mm];
            rank += km < ki;
          }
          if (rank < KNB) s_idx[q * KNB + rank] = cidx[q][i];
        }
      }
    }
    __syncthreads();

    // exact fallback (block-uniform branch; pathological only)
    for (int q = 0; q < QPB; ++q) {
      unsigned int n = scnt[q];
      if (n < KNB || n > CAP) {
        unsigned long long prev = 0ull;
        for (int r = 0; r < KNB; ++r) {
          unsigned long long best = ~0ull;
          for (int c = 0; c < NPTS / 256; ++c) {
            int j = c * 256 + tid;
            float dx = qx[q] - posb[j * 3 + 0];
            float dy = qy[q] - posb[j * 3 + 1];
            float dz = qz[q] - posb[j * 3 + 2];
            float d2 = fmaf(dz, dz, fmaf(dy, dy, dx * dx));
            unsigned long long key =
                ((unsigned long long)__float_as_uint(d2) << 32) |
                (unsigned int)j;
            bool ok = (r == 0) || (key > prev);
            best = (ok && key < best) ? key : best;
          }
#pragma unroll
          for (int off = 32; off > 0; off >>= 1) {
            unsigned long long o = __shfl_down(best, off);
            best = best < o ? best : o;
          }
          if (lane == 0) wmin[w] = best;
          __syncthreads();
          if (tid == 0) {
            unsigned long long m0 = wmin[0], m1 = wmin[1];
            unsigned long long m2 = wmin[2], m3 = wmin[3];
            unsigned long long a = m0 < m1 ? m0 : m1;
            unsigned long long d = m2 < m3 ? m2 : m3;
            a = a < d ? a : d;
            s_idx[q * KNB + r] = (int)(unsigned int)a;
            sprev[0] = a;
          }
          __syncthreads();
          prev = sprev[0];
          __syncthreads();
        }
      }
    }
  }
  __syncthreads();  // knn scratch dead; s_idx valid

  // ======================= attention phase =======================
  unsigned short(*region)[72] = (unsigned short(*)[72])smem;        // 18432
  float(*s_rel)[32][3] = (float(*)[32][3])(smem + 18432);           // 1536

  // staging: rel (parallel 32-lane gather)
  if (lane < 32) {
    int row = 32 * w + lane;
    int p = lane >> 4;
    int g = g0 + 2 * w + p;
    int jb = (b << 12) | s_idx[row];
    s_rel[w][lane][0] = pos[(size_t)g * 3 + 0] - pos[(size_t)jb * 3 + 0];
    s_rel[w][lane][1] = pos[(size_t)g * 3 + 1] - pos[(size_t)jb * 3 + 1];
    s_rel[w][lane][2] = pos[(size_t)g * 3 + 2] - pos[(size_t)jb * 3 + 2];
  }

  // phase2: e = relu(rel @ w_p1 + b_p1) -> region (s_e), wave rows
  {
    float w0 = w_p1[lane], w1 = w_p1[64 + lane], w2 = w_p1[128 + lane];
    float bp = b_p1[lane];
    for (int rl = 0; rl < 32; ++rl) {
      int row = 32 * w + rl;
      float rx = s_rel[w][rl][0], ry = s_rel[w][rl][1], rz = s_rel[w][rl][2];
      float e = fmaf(rz, w2, fmaf(ry, w1, fmaf(rx, w0, bp)));
      region[row][lane] = f2bf(fmaxf(e, 0.f));
    }
  }

  // phase3: pe MFMA + h epilogue; s_h overwrites s_e (frags in regs first)
  {
    bf16x8 ea0[2], ea1[2];
#pragma unroll
    for (int p = 0; p < 2; ++p) {
      ea0[p] = *(const bf16x8*)&region[32 * w + 16 * p + m][quad * 8];
      ea1[p] = *(const bf16x8*)&region[32 * w + 16 * p + m][32 + quad * 8];
    }
#pragma unroll
    for (int nt = 0; nt < 4; ++nt) {
      bf16x8 b0 = *(const bf16x8*)(pkp + ((size_t)(nt * 2 + 0) * 64 + lane) * 8);
      bf16x8 b1 = *(const bf16x8*)(pkp + ((size_t)(nt * 2 + 1) * 64 + lane) * 8);
      int col = nt * 16 + m;
      float bp2 = b_p2[col];
#pragma unroll
      for (int p = 0; p < 2; ++p) {
        f32x4 acc = {0.f, 0.f, 0.f, 0.f};
        acc = MFMA16(ea0[p], b0, acc);
        acc = MFMA16(ea1[p], b1, acc);
        int g = g0 + 2 * w + p;
        float qv = qkv[(size_t)g * 192 + col];
#pragma unroll
        for (int i = 0; i < 4; ++i) {
          int row = 32 * w + 16 * p + quad * 4 + i;
          int jb = (b << 12) | s_idx[row];
          float kv = qkv[(size_t)jb * 192 + 64 + col];
          region[row][col] = f2bf(qv - kv + acc[i] + bp2);  // s_h
        }
      }
    }
  }

  // v prefetch into registers (latency hidden behind GEMM1/2 below)
  float vreg[2][4][4];
#pragma unroll
  for (int p = 0; p < 2; ++p)
#pragma unroll
    for (int i = 0; i < 4; ++i) {
      int row = 32 * w + 16 * p + quad * 4 + i;
      int jb = (b << 12) | s_idx[row];
      const float* vr = qkv + (size_t)jb * 192 + 128;
#pragma unroll
      for (int nt2 = 0; nt2 < 4; ++nt2) vreg[p][nt2][i] = vr[nt2 * 16 + m];
    }

  // phase4+5: chunked GEMM1 -> s_tc (aliases own s_h rows) -> GEMM2 acc
  bf16x8 ha0[2], ha1[2];
#pragma unroll
  for (int p = 0; p < 2; ++p) {
    ha0[p] = *(const bf16x8*)&region[32 * w + 16 * p + m][quad * 8];
    ha1[p] = *(const bf16x8*)&region[32 * w + 16 * p + m][32 + quad * 8];
  }
  f32x4 acc2[2][4];
#pragma unroll
  for (int p = 0; p < 2; ++p)
#pragma unroll
    for (int nt2 = 0; nt2 < 4; ++nt2) acc2[p][nt2] = (f32x4){0.f, 0.f, 0.f, 0.f};

  unsigned short(*s_tc)[72] = (unsigned short(*)[72])(smem + w * 4608);

#pragma unroll
  for (int c = 0; c < 4; ++c) {
#pragma unroll
    for (int ntc = 0; ntc < 4; ++ntc) {
      int nt = 4 * c + ntc;
      bf16x8 b0 = *(const bf16x8*)(pk1 + ((size_t)(nt * 2 + 0) * 64 + lane) * 8);
      bf16x8 b1 = *(const bf16x8*)(pk1 + ((size_t)(nt * 2 + 1) * 64 + lane) * 8);
      int coll = ntc * 16 + m;
      float ba = b_a1[nt * 16 + m];
#pragma unroll
      for (int p = 0; p < 2; ++p) {
        f32x4 t = {0.f, 0.f, 0.f, 0.f};
        t = MFMA16(ha0[p], b0, t);
        t = MFMA16(ha1[p], b1, t);
#pragma unroll
        for (int i = 0; i < 4; ++i)
          s_tc[16 * p + quad * 4 + i][coll] = f2bf(fmaxf(t[i] + ba, 0.f));
      }
    }
#pragma unroll
    for (int sub = 0; sub < 2; ++sub) {
      int ks = c * 2 + sub;
      bf16x8 a[2];
#pragma unroll
      for (int p = 0; p < 2; ++p)
        a[p] = *(const bf16x8*)&s_tc[16 * p + m][sub * 32 + quad * 8];
#pragma unroll
      for (int nt2 = 0; nt2 < 4; ++nt2) {
        bf16x8 bb =
            *(const bf16x8*)(pk2 + ((size_t)(nt2 * 8 + ks) * 64 + lane) * 8);
#pragma unroll
        for (int p = 0; p < 2; ++p) acc2[p][nt2] = MFMA16(a[p], bb, acc2[p][nt2]);
      }
    }
  }

  // phase6: softmax over k (quad shuffles) + v-weighted sum (v from vreg)
  float ba2[4];
#pragma unroll
  for (int nt2 = 0; nt2 < 4; ++nt2) ba2[nt2] = b_a2[nt2 * 16 + m];
  float aggv[2][4];
#pragma unroll
  for (int p = 0; p < 2; ++p) {
#pragma unroll
    for (int nt2 = 0; nt2 < 4; ++nt2) {
      float sc[4];
#pragma unroll
      for (int i = 0; i < 4; ++i) sc[i] = acc2[p][nt2][i] + ba2[nt2];
      float mx = fmaxf(fmaxf(sc[0], sc[1]), fmaxf(sc[2], sc[3]));
      mx = fmaxf(mx, __shfl_xor(mx, 16));
      mx = fmaxf(mx, __shfl_xor(mx, 32));
      float ex[4], ss = 0.f;
#pragma unroll
      for (int i = 0; i < 4; ++i) {
        ex[i] = exp2f((sc[i] - mx) * 1.4426950408889634f);
        ss += ex[i];
      }
      ss += __shfl_xor(ss, 16);
      ss += __shfl_xor(ss, 32);
      float nu = 0.f;
#pragma unroll
      for (int i = 0; i < 4; ++i) nu = fmaf(ex[i], vreg[p][nt2][i], nu);
      nu += __shfl_xor(nu, 16);
      nu += __shfl_xor(nu, 32);
      aggv[p][nt2] = nu / ss;
    }
  }
  __syncthreads();  // all waves done with region -> reuse for agg/red

  float* s_agg = (float*)smem;  // [8][64]
  if (quad == 0) {
#pragma unroll
    for (int p = 0; p < 2; ++p)
#pragma unroll
      for (int nt2 = 0; nt2 < 4; ++nt2)
        s_agg[(2 * w + p) * 64 + nt2 * 16 + m] = aggv[p][nt2];
  }
  __syncthreads();

  // fc: thread (r=w, c=lane) handles rows w and w+4
  {
    int c = lane, r = w;
    float acc0 = b_fc[c], acc1 = b_fc[c];
    for (int d = 0; d < 64; ++d) {
      float wv = w_fc[d * 64 + c];
      acc0 = fmaf(s_agg[r * 64 + d], wv, acc0);
      acc1 = fmaf(s_agg[(r + 4) * 64 + d], wv, acc1);
    }
    y[(size_t)(g0 + r) * 64 + c] = acc0;
    y[(size_t)(g0 + r + 4) * 64 + c] = acc1;
    float* s_red = (float*)(smem + 2048);
    float* s_red2 = (float*)(smem + 3072);
    s_red[w * 64 + c] = acc0 + acc1;
    s_red2[w * 64 + c] = acc0 * acc0 + acc1 * acc1;
  }
  __syncthreads();
  if (tid < 64) {
    float* s_red = (float*)(smem + 1024 * 2);
    float* s_red2 = (float*)(smem + 1024 * 3);
    float s = s_red[tid] + s_red[64 + tid] + s_red[128 + tid] + s_red[192 + tid];
    float s2 =
        s_red2[tid] + s_red2[64 + tid] + s_red2[128 + tid] + s_red2[192 + tid];
    // R21: 8-way sharded stats -- avoids 1024 same-address atomic adds
    // (~50cy each = ~21us serialized tail). bn_kernel sums the shards.
    float* st = stats + (blockIdx.x & 7) * 128;
    atomicAdd(&st[tid], s);
    atomicAdd(&st[64 + tid], s2);
  }
}

// ---------------------------------------------------------------------------
// Kernel 3: BN (batch stats from 8 shards) + relu + residual.
// ---------------------------------------------------------------------------
__global__ __launch_bounds__(256) void bn_kernel(
    const float* __restrict__ y, const float* __restrict__ x,
    const float* __restrict__ stats, const float* __restrict__ gamma,
    const float* __restrict__ beta, float* __restrict__ out) {
  size_t o = (size_t)blockIdx.x * 256 + threadIdx.x;
  int c = (int)(o & 63);
  float s = 0.f, s2 = 0.f;
#pragma unroll
  for (int ch = 0; ch < 8; ++ch) {
    s += stats[ch * 128 + c];
    s2 += stats[ch * 128 + 64 + c];
  }
  const float inv_n = 1.f / 8192.f;
  float mean = s * inv_n;
  float var = s2 * inv_n - mean * mean;
  float inv = rsqrtf(var + 1e-5f);
  float v = (y[o] - mean) * inv * gamma[c] + beta[c];
  out[o] = fmaxf(v, 0.f) + x[o];
}

// ---------------------------------------------------------------------------
extern "C" void kernel_launch(void* const* d_in, const int* in_sizes, int n_in,
                              void* d_out, int out_size, void* d_ws,
                              size_t ws_size, hipStream_t stream) {
  const float* x = (const float*)d_in[0];
  const float* pos = (const float*)d_in[1];
  const float* w_qkv = (const float*)d_in[2];
  const float* b_qkv = (const float*)d_in[3];
  const float* w_p1 = (const float*)d_in[4];
  const float* b_p1 = (const float*)d_in[5];
  const float* w_p2 = (const float*)d_in[6];
  const float* b_p2 = (const float*)d_in[7];
  const float* w_a1 = (const float*)d_in[8];
  const float* b_a1 = (const float*)d_in[9];
  const float* w_a2 = (const float*)d_in[10];
  const float* b_a2 = (const float*)d_in[11];
  const float* w_fc = (const float*)d_in[12];
  const float* b_fc = (const float*)d_in[13];
  const float* gamma = (const float*)d_in[14];
  const float* beta = (const float*)d_in[15];

  char* ws = (char*)d_ws;
  float* qkv = (float*)(ws + 0);                           // 6291456 B
  float* y = (float*)(ws + 8912896);                       // 2097152 B
  float* stats = (float*)(ws + 11010048);                  // 4096 B (8x128)
  unsigned short* pk1 = (unsigned short*)(ws + 11014144);  // 32768 B
  unsigned short* pk2 = (unsigned short*)(ws + 11046912);  // 32768 B
  unsigned short* pkp = (unsigned short*)(ws + 11079680);  // 8192 B
  unsigned short* pkq = (unsigned short*)(ws + 11087872);  // 24576 B

  hipLaunchKernelGGL(pack_kernel, dim3(192), dim3(256), 0, stream, w_qkv,
                     w_a1, w_a2, w_p2, pkq, pk1, pk2, pkp, stats);
  hipLaunchKernelGGL(qkv_kernel, dim3(512), dim3(256), 0, stream, x, pkq,
                     b_qkv, qkv);
  hipLaunchKernelGGL(fused_kernel, dim3(1024), dim3(256), 0, stream, qkv, pos,
                     pk1, pk2, pkp, w_p1, b_p1, b_p2, b_a1, b_a2, w_fc, b_fc,
                     y, stats);
  hipLaunchKernelGGL(bn_kernel, dim3(2048), dim3(256), 0, stream, y, x, stats,
                     gamma, beta, (float*)d_out);
}